// Round 1
// baseline (30.445 us; speedup 1.0000x reference)
//
#include <hip/hip_runtime.h>
#include <math.h>

// SmoothedMedian: B=32, L=1024, C=32, w=32
// out[0..31] = M (per-batch max over t of windowed max distance)
// out[32..63] = R2 (per-batch sum over t of (windowed max distance)^2)

#define BB 32
#define LL 1024
#define CC 32
#define WW 32
#define TT 64                 // t-values per block
#define NROWS (TT + 2*WW)     // 128 rows staged (with halo)
#define STRIDE 33             // +1 pad: lane i, chan c -> bank (i+c)%32, 2-way alias = free
#define NTILES (LL / TT)      // 16

__global__ __launch_bounds__(64)
void sm_main(const float* __restrict__ x, float* __restrict__ ws) {
    const int b    = blockIdx.x;   // batch
    const int tile = blockIdx.y;   // t-tile
    const int t0   = tile * TT;
    const int tid  = threadIdx.x;  // 0..63, one wave

    __shared__ float lds[NROWS * STRIDE];

    const float* xb = x + (size_t)b * (LL * CC);

    // Cooperative staging: NROWS*CC = 4096 floats = 1024 float4, 16 per thread.
    // Rows outside [0,L) are zero-filled (never selected, but avoids inf/NaN).
    #pragma unroll
    for (int k = 0; k < (NROWS * CC / 4) / 64; ++k) {   // 16 iters
        const int f4 = tid + k * 64;
        const int rr = f4 >> 3;        // row within LDS tile (8 float4 per row)
        const int j  = f4 & 7;         // float4 slot within row
        const int rg = t0 - WW + rr;   // global row
        float4 v = make_float4(0.f, 0.f, 0.f, 0.f);
        if ((unsigned)rg < (unsigned)LL)
            v = *reinterpret_cast<const float4*>(xb + rg * CC + j * 4);
        float* p = &lds[rr * STRIDE + j * 4];
        p[0] = v.x; p[1] = v.y; p[2] = v.z; p[3] = v.w;
    }
    __syncthreads();

    const int t = t0 + tid;

    // Center row -> 32 VGPRs
    float cx[CC];
    #pragma unroll
    for (int c = 0; c < CC; ++c) cx[c] = lds[(tid + WW) * STRIDE + c];

    float maxd = 0.0f;   // o==0 contributes exactly 0, so 0 is the correct floor

    #pragma unroll 4
    for (int o = -WW; o <= WW; ++o) {
        const int r = t + o;
        const float* row = &lds[(tid + WW + o) * STRIDE];
        float a0 = 0.f, a1 = 0.f, a2 = 0.f, a3 = 0.f;
        #pragma unroll
        for (int c = 0; c < CC; c += 4) {
            const float d0 = cx[c]     - row[c];
            const float d1 = cx[c + 1] - row[c + 1];
            const float d2 = cx[c + 2] - row[c + 2];
            const float d3 = cx[c + 3] - row[c + 3];
            a0 = fmaf(d0, d0, a0);
            a1 = fmaf(d1, d1, a1);
            a2 = fmaf(d2, d2, a2);
            a3 = fmaf(d3, d3, a3);
        }
        const float sq = (a0 + a1) + (a2 + a3);
        // valid window position AND sq>0 (matches reference's where(sq>0, sqrt, 0))
        const float dist = (sq > 0.0f && (unsigned)r < (unsigned)LL)
                               ? sqrtf(sq) * (1.0f / CC) : 0.0f;
        maxd = fmaxf(maxd, dist);
    }

    // Wave (=block) reduction: max and sum-of-squares. Deterministic tree order.
    float m  = maxd;
    float r2 = maxd * maxd;
    #pragma unroll
    for (int s = 1; s < 64; s <<= 1) {
        m  = fmaxf(m, __shfl_xor(m, s));
        r2 += __shfl_xor(r2, s);
    }

    if (tid == 0) {
        float* slot = ws + (size_t)(b * NTILES + tile) * 2;
        slot[0] = m;
        slot[1] = r2;
    }
}

__global__ __launch_bounds__(64)
void sm_reduce(const float* __restrict__ ws, float* __restrict__ out) {
    const int b = threadIdx.x;
    if (b < BB) {
        float m = 0.f, r2 = 0.f;
        for (int k = 0; k < NTILES; ++k) {
            m   = fmaxf(m, ws[(size_t)(b * NTILES + k) * 2]);
            r2 +=           ws[(size_t)(b * NTILES + k) * 2 + 1];
        }
        out[b]      = m;   // M
        out[BB + b] = r2;  // R2
    }
}

extern "C" void kernel_launch(void* const* d_in, const int* in_sizes, int n_in,
                              void* d_out, int out_size, void* d_ws, size_t ws_size,
                              hipStream_t stream) {
    const float* x  = (const float*)d_in[0];   // (32,1024,32) fp32
    // d_in[1] is w == 32, hardcoded
    float* ws  = (float*)d_ws;                 // 32*16*2 floats = 4 KB
    float* out = (float*)d_out;                // 64 floats: M(32) ++ R2(32)

    sm_main<<<dim3(BB, NTILES), 64, 0, stream>>>(x, ws);
    sm_reduce<<<1, 64, 0, stream>>>(ws, out);
}

// Round 2
// 12.114 us; speedup vs baseline: 2.5131x; 2.5131x over previous
//
#include <hip/hip_runtime.h>
#include <math.h>

// SmoothedMedian: B=32, L=1024, C=32, w=32
// out[0..31] = M (per-batch max over t of windowed max distance)
// out[32..63] = R2 (per-batch sum over t of (windowed max distance)^2)
//
// dist(t,j) = sqrt(||x_t - x_j||^2)/32, window |j-t|<=32, j in [0,L).
// o=0 gives exactly 0, so only the 64 nonzero offsets matter; they are
// split into 8 groups of 8 across the block's 8 thread-groups.
// sq computed in dot form: sq = n_t + n_j - 2*dot(x_t,x_j), norms precomputed.

#define BB 32
#define LL 1024
#define CC 32
#define WW 32
#define TT 32                  // t-values per block
#define NROWS (TT + 2*WW)      // 96 rows staged (with halo)
#define STRIDE 36              // 144B rows: 16B-aligned for ds_read_b128,
                               // lane i row i+const -> base bank 4i%32 (full coverage)
#define NTILES (LL / TT)       // 32

__global__ __launch_bounds__(256)
void sm_main(const float* __restrict__ x, float* __restrict__ ws) {
    const int b    = blockIdx.x;    // batch
    const int tile = blockIdx.y;    // t-tile
    const int t0   = tile * TT;
    const int tid  = threadIdx.x;   // 0..255
    const int ln   = tid & 31;      // t index within tile
    const int g    = tid >> 5;      // offset group 0..7

    __shared__ __align__(16) float lds[NROWS * STRIDE];
    __shared__ float nrm[NROWS];
    __shared__ float red[8 * TT];

    const float* xb = x + (size_t)b * (LL * CC);

    // --- stage 96 rows x 32 ch: 768 float4, 3 per thread, coalesced ---
    #pragma unroll
    for (int k = 0; k < 3; ++k) {
        const int f4 = tid + k * 256;
        const int rr = f4 >> 3;        // local row (8 float4 per row)
        const int j  = f4 & 7;
        const int rg = t0 - WW + rr;   // global row
        float4 v = make_float4(0.f, 0.f, 0.f, 0.f);
        if ((unsigned)rg < (unsigned)LL)
            v = *reinterpret_cast<const float4*>(xb + rg * CC + j * 4);
        float* p = &lds[rr * STRIDE + j * 4];
        p[0] = v.x; p[1] = v.y; p[2] = v.z; p[3] = v.w;
    }
    __syncthreads();

    // --- per-row squared norms (threads 0..95, lanes read consecutive rows) ---
    if (tid < NROWS) {
        const float4* row = reinterpret_cast<const float4*>(&lds[tid * STRIDE]);
        float a0 = 0.f, a1 = 0.f, a2 = 0.f, a3 = 0.f;
        #pragma unroll
        for (int j = 0; j < 8; ++j) {
            const float4 v = row[j];
            a0 = fmaf(v.x, v.x, a0);
            a1 = fmaf(v.y, v.y, a1);
            a2 = fmaf(v.z, v.z, a2);
            a3 = fmaf(v.w, v.w, a3);
        }
        nrm[tid] = (a0 + a1) + (a2 + a3);
    }
    __syncthreads();

    // --- center row into registers ---
    const int cr = ln + WW;            // local center row
    float4 cx[8];
    const float4* crow = reinterpret_cast<const float4*>(&lds[cr * STRIDE]);
    #pragma unroll
    for (int j = 0; j < 8; ++j) cx[j] = crow[j];
    const float nc = nrm[cr];

    // offset group g covers 8 contiguous nonzero offsets
    const int a_g = (g < 4) ? (8 * g - 32) : (8 * g - 31);

    float maxsq = 0.0f;  // o==0 contributes exactly 0 -> correct floor
    #pragma unroll 2
    for (int k = 0; k < 8; ++k) {
        const int lr = cr + a_g + k;                  // local window row
        const float4* row = reinterpret_cast<const float4*>(&lds[lr * STRIDE]);
        float a0 = 0.f, a1 = 0.f, a2 = 0.f, a3 = 0.f;
        #pragma unroll
        for (int j = 0; j < 8; ++j) {
            const float4 v = row[j];
            a0 = fmaf(cx[j].x, v.x, a0);
            a1 = fmaf(cx[j].y, v.y, a1);
            a2 = fmaf(cx[j].z, v.z, a2);
            a3 = fmaf(cx[j].w, v.w, a3);
        }
        const float dot = (a0 + a1) + (a2 + a3);
        const float sq  = nc + nrm[lr] - 2.0f * dot;
        const int rg = t0 - WW + lr;                  // global window row
        if ((unsigned)rg < (unsigned)LL)
            maxsq = fmaxf(maxsq, sq);
    }
    red[g * TT + ln] = maxsq;
    __syncthreads();

    // --- combine 8 groups per t, then block reduce (lanes 0..31 of wave 0) ---
    if (tid < TT) {
        float m = red[tid];
        #pragma unroll
        for (int gg = 1; gg < 8; ++gg) m = fmaxf(m, red[gg * TT + tid]);
        const float d  = sqrtf(m) * (1.0f / CC);   // m >= 0 by construction
        float dm = d;
        float r2 = d * d;
        #pragma unroll
        for (int s = 1; s < 32; s <<= 1) {
            dm  = fmaxf(dm, __shfl_xor(dm, s));
            r2 += __shfl_xor(r2, s);
        }
        if (tid == 0) {
            float* slot = ws + (size_t)(b * NTILES + tile) * 2;
            slot[0] = dm;
            slot[1] = r2;
        }
    }
}

__global__ __launch_bounds__(64)
void sm_reduce(const float* __restrict__ ws, float* __restrict__ out) {
    const int b = threadIdx.x;
    if (b < BB) {
        float m = 0.f, r2 = 0.f;
        for (int k = 0; k < NTILES; ++k) {
            m   = fmaxf(m, ws[(size_t)(b * NTILES + k) * 2]);
            r2 +=           ws[(size_t)(b * NTILES + k) * 2 + 1];
        }
        out[b]      = m;   // M
        out[BB + b] = r2;  // R2
    }
}

extern "C" void kernel_launch(void* const* d_in, const int* in_sizes, int n_in,
                              void* d_out, int out_size, void* d_ws, size_t ws_size,
                              hipStream_t stream) {
    const float* x  = (const float*)d_in[0];   // (32,1024,32) fp32
    // d_in[1] is w == 32, hardcoded
    float* ws  = (float*)d_ws;                 // 32*32*2 floats = 8 KB
    float* out = (float*)d_out;                // 64 floats: M(32) ++ R2(32)

    sm_main<<<dim3(BB, NTILES), 256, 0, stream>>>(x, ws);
    sm_reduce<<<1, 64, 0, stream>>>(ws, out);
}

// Round 3
// 11.500 us; speedup vs baseline: 2.6473x; 1.0534x over previous
//
#include <hip/hip_runtime.h>
#include <math.h>

// SmoothedMedian: B=32, L=1024, C=32, w=32
// out[0..31] = M (per-batch max over t of windowed max distance)
// out[32..63] = R2 (per-batch sum over t of (windowed max distance)^2)
//
// Per (batch, 32-center tile): banded Gram G[t,r] = dot(x_t, x_r) over the
// 96 staged window rows via split-bf16 MFMA (x = hi + lo, bit-truncated):
//   G ~= Ah*Bh^T + Ah*Bl^T + Al*Bh^T   (error ~2^-16 relative)
//   sq(t,r) = n_t + n_r - 2*G[t,r]     (norms exact fp32)
//   maxsq[t] = max over valid r (r-t in [0,64] local, global row in [0,L))
// mfma_f32_16x16x32_bf16: A lane l -> row l&15, k=(l>>4)*8+j (K-contig);
// B lane l -> col l&15, k=(l>>4)*8+j; D: col=l&15, row=(l>>4)*4+reg.

#define BB 32
#define LL 1024
#define CC 32
#define WW 32
#define TT 32
#define NROWS (TT + 2*WW)     // 96
#define PADH 40               // bf16 elems/row (80 B): 16B-aligned, bank-spread
#define NTILES (LL / TT)      // 32

typedef __attribute__((ext_vector_type(8))) short bf16x8;
typedef __attribute__((ext_vector_type(4))) float f32x4;

__global__ __launch_bounds__(128)
void sm_main(const float* __restrict__ x, float* __restrict__ ws) {
    const int b    = blockIdx.x;
    const int tile = blockIdx.y;
    const int t0   = tile * TT;
    const int tid  = threadIdx.x;   // 0..127
    const int l    = tid & 63;      // lane
    const int w    = tid >> 6;      // wave 0..1

    __shared__ __align__(16) unsigned short hi[NROWS * PADH];
    __shared__ __align__(16) unsigned short lo[NROWS * PADH];
    __shared__ __align__(16) float nrm_part[NROWS * 8];
    __shared__ float nrm[NROWS];
    __shared__ float redm[8], redr[8];

    const float* xb = x + (size_t)b * (LL * CC);

    // --- stage 96 rows x 32 ch: load fp32, split to bf16 hi/lo, norm partials ---
    #pragma unroll
    for (int k = 0; k < 6; ++k) {
        const int f4 = tid + k * 128;      // 0..767
        const int rr = f4 >> 3;            // local row (8 float4/row)
        const int j  = f4 & 7;
        const int rg = t0 - WW + rr;       // global row
        float4 v = make_float4(0.f, 0.f, 0.f, 0.f);
        if ((unsigned)rg < (unsigned)LL)
            v = *reinterpret_cast<const float4*>(xb + rg * CC + j * 4);
        float vv[4] = {v.x, v.y, v.z, v.w};
        unsigned short hb[4], lb[4];
        float s = 0.f;
        #pragma unroll
        for (int e = 0; e < 4; ++e) {
            const float xe = vv[e];
            const unsigned ux = __float_as_uint(xe);
            hb[e] = (unsigned short)(ux >> 16);                  // truncate to bf16
            const float hf = __uint_as_float(ux & 0xFFFF0000u);
            const float lf = xe - hf;                            // exact
            lb[e] = (unsigned short)(__float_as_uint(lf) >> 16); // truncate
            s = fmaf(xe, xe, s);
        }
        *reinterpret_cast<ushort4*>(&hi[rr * PADH + j * 4]) = make_ushort4(hb[0], hb[1], hb[2], hb[3]);
        *reinterpret_cast<ushort4*>(&lo[rr * PADH + j * 4]) = make_ushort4(lb[0], lb[1], lb[2], lb[3]);
        nrm_part[f4] = s;
    }
    __syncthreads();

    if (tid < NROWS) {
        const float4* p = reinterpret_cast<const float4*>(&nrm_part[tid * 8]);
        const float4 a = p[0], c = p[1];
        nrm[tid] = ((a.x + a.y) + (a.z + a.w)) + ((c.x + c.y) + (c.z + c.w));
    }
    __syncthreads();

    // --- A-frag: wave w's 16 centers (local rows 32+16w .. 32+16w+15) ---
    const int kc = (l >> 4) * 8;                 // channel offset of this lane's 8 elems
    const int ar = 32 + 16 * w + (l & 15);       // A row
    const bf16x8 Ah = *reinterpret_cast<const bf16x8*>(&hi[ar * PADH + kc]);
    const bf16x8 Al = *reinterpret_cast<const bf16x8*>(&lo[ar * PADH + kc]);

    const int col = l & 15;
    float maxsq[4] = {0.f, 0.f, 0.f, 0.f};       // o==0 gives ~0; floor 0 is correct

    #pragma unroll
    for (int ct = 0; ct < 6; ++ct) {
        const int br = ct * 16 + col;            // B row = local window row of this lane's col
        const bf16x8 Bh = *reinterpret_cast<const bf16x8*>(&hi[br * PADH + kc]);
        const bf16x8 Bl = *reinterpret_cast<const bf16x8*>(&lo[br * PADH + kc]);
        f32x4 acc = {0.f, 0.f, 0.f, 0.f};
        acc = __builtin_amdgcn_mfma_f32_16x16x32_bf16(Ah, Bh, acc, 0, 0, 0);
        acc = __builtin_amdgcn_mfma_f32_16x16x32_bf16(Ah, Bl, acc, 0, 0, 0);
        acc = __builtin_amdgcn_mfma_f32_16x16x32_bf16(Al, Bh, acc, 0, 0, 0);

        const int r  = br;                       // lane's window row for this tile
        const int rg = t0 - WW + r;              // global window row
        const float nr = nrm[r];
        #pragma unroll
        for (int i = 0; i < 4; ++i) {
            const int t = 16 * w + (l >> 4) * 4 + i;   // center local index 0..31
            // window validity: r in [t, t+64]; global row in range
            if (r >= t && r <= t + 64 && (unsigned)rg < (unsigned)LL) {
                const float sq = nrm[t + 32] + nr - 2.0f * acc[i];
                maxsq[i] = fmaxf(maxsq[i], sq);
            }
        }
    }

    // --- reduce over the 16 lanes sharing the same 4 centers (cols) ---
    #pragma unroll
    for (int i = 0; i < 4; ++i) {
        float m = maxsq[i];
        #pragma unroll
        for (int s = 1; s < 16; s <<= 1) m = fmaxf(m, __shfl_xor(m, s));
        maxsq[i] = m;
    }
    if ((l & 15) == 0) {
        float dm = 0.f, r2 = 0.f;
        #pragma unroll
        for (int i = 0; i < 4; ++i) {
            const float d = sqrtf(fmaxf(maxsq[i], 0.f)) * (1.0f / CC);
            dm = fmaxf(dm, d);
            r2 = fmaf(d, d, r2);
        }
        redm[w * 4 + (l >> 4)] = dm;
        redr[w * 4 + (l >> 4)] = r2;
    }
    __syncthreads();

    if (tid == 0) {
        float dm = redm[0], r2 = redr[0];
        #pragma unroll
        for (int g = 1; g < 8; ++g) { dm = fmaxf(dm, redm[g]); r2 += redr[g]; }
        float* slot = ws + (size_t)(b * NTILES + tile) * 2;
        slot[0] = dm;
        slot[1] = r2;
    }
}

__global__ __launch_bounds__(64)
void sm_reduce(const float* __restrict__ ws, float* __restrict__ out) {
    const int b = threadIdx.x;
    if (b < BB) {
        float m = 0.f, r2 = 0.f;
        for (int k = 0; k < NTILES; ++k) {
            m   = fmaxf(m, ws[(size_t)(b * NTILES + k) * 2]);
            r2 +=           ws[(size_t)(b * NTILES + k) * 2 + 1];
        }
        out[b]      = m;   // M
        out[BB + b] = r2;  // R2
    }
}

extern "C" void kernel_launch(void* const* d_in, const int* in_sizes, int n_in,
                              void* d_out, int out_size, void* d_ws, size_t ws_size,
                              hipStream_t stream) {
    const float* x  = (const float*)d_in[0];   // (32,1024,32) fp32
    // d_in[1] is w == 32, hardcoded
    float* ws  = (float*)d_ws;                 // 32*32*2 floats = 8 KB
    float* out = (float*)d_out;                // 64 floats: M(32) ++ R2(32)

    sm_main<<<dim3(BB, NTILES), 128, 0, stream>>>(x, ws);
    sm_reduce<<<1, 64, 0, stream>>>(ws, out);
}